// Round 7
// baseline (929.213 us; speedup 1.0000x reference)
//
#include <hip/hip_runtime.h>

#define HH 512
#define WW 512
#define NPIX (HH * WW)          // 262144
#define NIMG 16
#define KPTS 1024
#define NWORDS (NPIX / 64)      // 4096 u64 mask words per image

// ---------------------------------------------------------------------------
// Kernel 1: binarize + uniform LBP (P=8,R=1) + ballot-pack mask bits
// ---------------------------------------------------------------------------
__global__ void lbp_kernel(const float* __restrict__ mo,
                           const float* __restrict__ lb,
                           unsigned long long* __restrict__ maskbits) {
#pragma clang fp contract(off)
    int m = blockIdx.y;                    // image 0..15: even=pred, odd=mask
    int pix = blockIdx.x * blockDim.x + threadIdx.x;   // 0..262143
    int r = pix >> 9, c = pix & 511;
    int sample = m >> 1;
    const float* img = (m & 1) ? (lb + sample * NPIX) : (mo + sample * NPIX);
    float thr = (m & 1) ? 0.5f : 0.0f;     // sigmoid(x)>0.5 <=> x>0

    float center = img[pix] > thr ? 1.0f : 0.0f;

    const float A = 0.70710678f;           // np.round(sin/cos, 8)
    const float drs[8] = {0.f, -A, -1.f, -A, 0.f,  A, 1.f, A};
    const float dcs[8] = {1.f,  A,  0.f, -A, -1.f, -A, 0.f, A};

    unsigned bb = 0u;
#pragma unroll
    for (int k = 0; k < 8; k++) {
        float rr = (float)r + drs[k];
        float cc = (float)c + dcs[k];
        float r0 = floorf(rr), c0 = floorf(cc);
        float fr = rr - r0,   fc = cc - c0;
        int r0i = (int)r0; r0i = max(0, min(HH - 1, r0i));
        int c0i = (int)c0; c0i = max(0, min(WW - 1, c0i));
        int r1i = min(HH - 1, r0i + 1);
        int c1i = min(WW - 1, c0i + 1);
        float g00 = img[r0i * WW + c0i] > thr ? 1.0f : 0.0f;
        float g01 = img[r0i * WW + c1i] > thr ? 1.0f : 0.0f;
        float g10 = img[r1i * WW + c0i] > thr ? 1.0f : 0.0f;
        float g11 = img[r1i * WW + c1i] > thr ? 1.0f : 0.0f;
        float s1 = (1.0f - fc) * g00 + fc * g01;
        float s2 = (1.0f - fc) * g10 + fc * g11;
        float smp = (1.0f - fr) * s1 + fr * s2;
        if (smp - center >= 0.0f) bb |= (1u << k);
    }
    unsigned rol = ((bb << 1) | (bb >> 7)) & 0xFFu;
    int changes = __popc(bb ^ rol);
    int s = __popc(bb);
    bool maskbit = (changes <= 2) && (s < 5);   // lbp < THR(=5)

    unsigned long long w = __ballot(maskbit);
    if ((threadIdx.x & 63) == 0)
        maskbits[m * NWORDS + (pix >> 6)] = w;
}

// ---------------------------------------------------------------------------
// Kernel 2: stable row-major compaction to K=1024 packed points per image
// pts entry: (r<<16)|c ; zero-padded. Shfl scan + uniform early-exit once
// K points are found (random inputs -> chunk 0 already has ~2x K).
// ---------------------------------------------------------------------------
__global__ void select_kernel(const unsigned long long* __restrict__ maskbits,
                              unsigned* __restrict__ ptsG) {
    __shared__ unsigned swv[4];
    int m = blockIdx.x, tid = threadIdx.x;
    int lane = tid & 63, wid = tid >> 6;

    for (int i = tid; i < KPTS; i += 256) ptsG[m * KPTS + i] = 0u;
    __syncthreads();

    unsigned running = 0;
    for (int ch = 0; ch < 16; ch++) {
        int w = ch * 256 + tid;
        unsigned long long word = maskbits[m * NWORDS + w];
        unsigned cnt = (unsigned)__popcll(word);

        unsigned x = cnt;                    // intra-wave inclusive scan
#pragma unroll
        for (int d = 1; d < 64; d <<= 1) {
            unsigned y = (unsigned)__shfl_up((int)x, d, 64);
            x += (lane >= d) ? y : 0u;
        }
        if (lane == 63) swv[wid] = x;
        __syncthreads();
        unsigned woff = 0, total = 0;
#pragma unroll
        for (int ww = 0; ww < 4; ww++) {
            unsigned t = swv[ww];
            total += t;
            woff += (ww < wid) ? t : 0u;
        }
        unsigned rank = running + woff + x - cnt;   // exclusive prefix
        while (word) {
            int b = __builtin_ctzll(word);
            word &= word - 1;
            if (rank < (unsigned)KPTS) {
                unsigned p = (unsigned)(w * 64 + b);
                unsigned rr = p >> 9, cc = p & 511u;
                ptsG[m * KPTS + rank] = (rr << 16) | cc;
            }
            rank++;
        }
        running += total;
        if (running >= (unsigned)KPTS) break;   // uniform -> safe
        __syncthreads();   // protect swv before next chunk
    }
}

// ---------------------------------------------------------------------------
// Kernel 3 (phase 1): DUAL-IMAGE single-wave Prim, RECORD-ONLY, ZERO LDS.
// One wave interleaves TWO independent Prim chains (images 2b, 2b+1) so
// chain-B issue fills chain-A latency bubbles (R6: 86% stall @ 1 chain).
// key = (d2<<10)|idx : unsigned-min == argmin w/ first-index ties;
// in-tree key = 0xFFFFFFFF (signed -1 so update '<' never wins).
// ---------------------------------------------------------------------------
typedef short v2s __attribute__((ext_vector_type(2)));

__device__ __forceinline__ int dist2_packed(unsigned a, unsigned b) {
#if __has_builtin(__builtin_amdgcn_sdot2)
    v2s d = __builtin_bit_cast(v2s, a) - __builtin_bit_cast(v2s, b);
    return __builtin_amdgcn_sdot2(d, d, 0, false);
#else
    int dr = (int)(a >> 16) - (int)(b >> 16);
    int dc = (int)(a & 0xFFFFu) - (int)(b & 0xFFFFu);
    return __mul24(dr, dr) + __mul24(dc, dc);
#endif
}

template <int CTRL>
__device__ __forceinline__ unsigned umin_dpp(unsigned x) {
    unsigned o = (unsigned)__builtin_amdgcn_update_dpp((int)x, (int)x, CTRL,
                                                       0xf, 0xf, false);
    return o < x ? o : x;
}

__device__ __forceinline__ unsigned umin3(unsigned a, unsigned b, unsigned c) {
    unsigned t = a < b ? a : b;          // fuses to v_min3_u32
    return t < c ? t : c;
}

#define SLOT_INIT(s, ps, ks, bs, p00)                                     \
    ps = bs[(s << 6) | lane];                                             \
    { int _d2 = dist2_packed(ps, p00);                                    \
      ks = ((unsigned)_d2 << 10) | (unsigned)((s << 6) | lane); }

#define SLOT_UPD(s, ps, ks, is, pj2, hit, wslot)                          \
    { v2s _d = __builtin_bit_cast(v2s, ps) - pj2;                         \
      int _d2 = __builtin_amdgcn_sdot2(_d, _d, 0, false);                 \
      unsigned _nk = ((unsigned)_d2 << 10) | is;                          \
      ks = ((int)_nk < (int)ks) ? _nk : ks;                               \
      ks = (hit && ((wslot) == (s))) ? 0xFFFFFFFFu : ks; }

#define INLANE_MIN16(res, K)                                              \
    { unsigned _m0 = umin3(K##0, K##1, K##2);                             \
      unsigned _m1 = umin3(K##3, K##4, K##5);                             \
      unsigned _m2 = umin3(K##6, K##7, K##8);                             \
      unsigned _m3 = umin3(K##9, K##10, K##11);                           \
      unsigned _m4 = umin3(K##12, K##13, K##14);                          \
      unsigned _ra = umin3(_m0, _m1, _m2);                                \
      unsigned _rb = umin3(_m3, _m4, K##15);                              \
      res = _ra < _rb ? _ra : _rb; }

#define SEL16(res, P, b0, b1, b2, b3)                                     \
    { unsigned _a0 = b0 ? P##1  : P##0;                                   \
      unsigned _a1 = b0 ? P##3  : P##2;                                   \
      unsigned _a2 = b0 ? P##5  : P##4;                                   \
      unsigned _a3 = b0 ? P##7  : P##6;                                   \
      unsigned _a4 = b0 ? P##9  : P##8;                                   \
      unsigned _a5 = b0 ? P##11 : P##10;                                  \
      unsigned _a6 = b0 ? P##13 : P##12;                                  \
      unsigned _a7 = b0 ? P##15 : P##14;                                  \
      unsigned _c0 = b1 ? _a1 : _a0;                                      \
      unsigned _c1 = b1 ? _a3 : _a2;                                      \
      unsigned _c2 = b1 ? _a5 : _a4;                                      \
      unsigned _c3 = b1 ? _a7 : _a6;                                      \
      unsigned _e0 = b2 ? _c1 : _c0;                                      \
      unsigned _e1 = b2 ? _c3 : _c2;                                      \
      res = b3 ? _e1 : _e0; }

#define PIN16(P) asm volatile("" :                                        \
    "+v"(P##0), "+v"(P##1), "+v"(P##2),  "+v"(P##3),                      \
    "+v"(P##4), "+v"(P##5), "+v"(P##6),  "+v"(P##7),                      \
    "+v"(P##8), "+v"(P##9), "+v"(P##10), "+v"(P##11),                     \
    "+v"(P##12), "+v"(P##13), "+v"(P##14), "+v"(P##15))

__global__ __launch_bounds__(64, 1) void mst_kernel(const unsigned* __restrict__ ptsG,
                                                    unsigned* __restrict__ edgesG) {
    int lane = threadIdx.x;          // 0..63
    int mA = blockIdx.x * 2;         // pred image
    int mB = mA + 1;                 // mask image (independent chain)
    const unsigned* baseA = ptsG + mA * KPTS;
    const unsigned* baseB = ptsG + mB * KPTS;
    unsigned ptA0 = baseA[0];
    unsigned ptB0 = baseB[0];

    unsigned kA0,kA1,kA2,kA3,kA4,kA5,kA6,kA7,kA8,kA9,kA10,kA11,kA12,kA13,kA14,kA15;
    unsigned pA0,pA1,pA2,pA3,pA4,pA5,pA6,pA7,pA8,pA9,pA10,pA11,pA12,pA13,pA14,pA15;
    unsigned kB0,kB1,kB2,kB3,kB4,kB5,kB6,kB7,kB8,kB9,kB10,kB11,kB12,kB13,kB14,kB15;
    unsigned pB0,pB1,pB2,pB3,pB4,pB5,pB6,pB7,pB8,pB9,pB10,pB11,pB12,pB13,pB14,pB15;
    unsigned i0,i1,i2,i3,i4,i5,i6,i7,i8,i9,i10,i11,i12,i13,i14,i15;

    i0=(0<<6)|lane;   i1=(1<<6)|lane;   i2=(2<<6)|lane;   i3=(3<<6)|lane;
    i4=(4<<6)|lane;   i5=(5<<6)|lane;   i6=(6<<6)|lane;   i7=(7<<6)|lane;
    i8=(8<<6)|lane;   i9=(9<<6)|lane;   i10=(10<<6)|lane; i11=(11<<6)|lane;
    i12=(12<<6)|lane; i13=(13<<6)|lane; i14=(14<<6)|lane; i15=(15<<6)|lane;

    SLOT_INIT(0,  pA0,  kA0,  baseA, ptA0);  SLOT_INIT(0,  pB0,  kB0,  baseB, ptB0);
    SLOT_INIT(1,  pA1,  kA1,  baseA, ptA0);  SLOT_INIT(1,  pB1,  kB1,  baseB, ptB0);
    SLOT_INIT(2,  pA2,  kA2,  baseA, ptA0);  SLOT_INIT(2,  pB2,  kB2,  baseB, ptB0);
    SLOT_INIT(3,  pA3,  kA3,  baseA, ptA0);  SLOT_INIT(3,  pB3,  kB3,  baseB, ptB0);
    SLOT_INIT(4,  pA4,  kA4,  baseA, ptA0);  SLOT_INIT(4,  pB4,  kB4,  baseB, ptB0);
    SLOT_INIT(5,  pA5,  kA5,  baseA, ptA0);  SLOT_INIT(5,  pB5,  kB5,  baseB, ptB0);
    SLOT_INIT(6,  pA6,  kA6,  baseA, ptA0);  SLOT_INIT(6,  pB6,  kB6,  baseB, ptB0);
    SLOT_INIT(7,  pA7,  kA7,  baseA, ptA0);  SLOT_INIT(7,  pB7,  kB7,  baseB, ptB0);
    SLOT_INIT(8,  pA8,  kA8,  baseA, ptA0);  SLOT_INIT(8,  pB8,  kB8,  baseB, ptB0);
    SLOT_INIT(9,  pA9,  kA9,  baseA, ptA0);  SLOT_INIT(9,  pB9,  kB9,  baseB, ptB0);
    SLOT_INIT(10, pA10, kA10, baseA, ptA0);  SLOT_INIT(10, pB10, kB10, baseB, ptB0);
    SLOT_INIT(11, pA11, kA11, baseA, ptA0);  SLOT_INIT(11, pB11, kB11, baseB, ptB0);
    SLOT_INIT(12, pA12, kA12, baseA, ptA0);  SLOT_INIT(12, pB12, kB12, baseB, ptB0);
    SLOT_INIT(13, pA13, kA13, baseA, ptA0);  SLOT_INIT(13, pB13, kB13, baseB, ptB0);
    SLOT_INIT(14, pA14, kA14, baseA, ptA0);  SLOT_INIT(14, pB14, kB14, baseB, ptB0);
    SLOT_INIT(15, pA15, kA15, baseA, ptA0);  SLOT_INIT(15, pB15, kB15, baseB, ptB0);

    kA0 = (lane == 0) ? 0xFFFFFFFFu : kA0;   // in_tree[0] = True
    kB0 = (lane == 0) ? 0xFFFFFFFFu : kB0;

    unsigned* eoutA = edgesG + mA * KPTS;
    unsigned* eoutB = edgesG + mB * KPTS;
    unsigned rkA, rkB;
    INLANE_MIN16(rkA, kA);
    INLANE_MIN16(rkB, kB);

    for (int it = 0; it < KPTS - 1; it++) {
        PIN16(pA); PIN16(kA); PIN16(pB); PIN16(kB);

        // ---- wave-64 min, both chains interleaved (independent) ----
        rkA = umin_dpp<0x111>(rkA);  rkB = umin_dpp<0x111>(rkB);
        rkA = umin_dpp<0x112>(rkA);  rkB = umin_dpp<0x112>(rkB);
        rkA = umin_dpp<0x114>(rkA);  rkB = umin_dpp<0x114>(rkB);
        rkA = umin_dpp<0x118>(rkA);  rkB = umin_dpp<0x118>(rkB);
        unsigned qA0 = (unsigned)__builtin_amdgcn_readlane((int)rkA, 15);
        unsigned qA1 = (unsigned)__builtin_amdgcn_readlane((int)rkA, 31);
        unsigned qA2 = (unsigned)__builtin_amdgcn_readlane((int)rkA, 47);
        unsigned qA3 = (unsigned)__builtin_amdgcn_readlane((int)rkA, 63);
        unsigned qB0 = (unsigned)__builtin_amdgcn_readlane((int)rkB, 15);
        unsigned qB1 = (unsigned)__builtin_amdgcn_readlane((int)rkB, 31);
        unsigned qB2 = (unsigned)__builtin_amdgcn_readlane((int)rkB, 47);
        unsigned qB3 = (unsigned)__builtin_amdgcn_readlane((int)rkB, 63);
        unsigned waA = qA0 < qA1 ? qA0 : qA1;
        unsigned wbA = qA2 < qA3 ? qA2 : qA3;
        unsigned wkA = waA < wbA ? waA : wbA;    // scalar, uniform
        unsigned waB = qB0 < qB1 ? qB0 : qB1;
        unsigned wbB = qB2 < qB3 ? qB2 : qB3;
        unsigned wkB = waB < wbB ? waB : wbB;

        unsigned jA = wkA & 1023u;
        unsigned jB = wkB & 1023u;
        int wslotA = (int)(jA >> 6), wlaneA = (int)(jA & 63u);
        int wslotB = (int)(jB >> 6), wlaneB = (int)(jB & 63u);

        if (lane == 0) {                     // record edges (fire-and-forget)
            eoutA[it] = wkA;
            eoutB[it] = wkB;
        }

        // ---- pj from the register file: SEL16 tree + readlane ----
        bool a0 = (wslotA & 1) != 0, a1 = (wslotA & 2) != 0;
        bool a2 = (wslotA & 4) != 0, a3 = (wslotA & 8) != 0;
        bool c0 = (wslotB & 1) != 0, c1 = (wslotB & 2) != 0;
        bool c2 = (wslotB & 4) != 0, c3 = (wslotB & 8) != 0;
        unsigned selA, selB;
        SEL16(selA, pA, a0, a1, a2, a3);
        SEL16(selB, pB, c0, c1, c2, c3);
        unsigned pjA = (unsigned)__builtin_amdgcn_readlane((int)selA, wlaneA);
        unsigned pjB = (unsigned)__builtin_amdgcn_readlane((int)selB, wlaneB);
        v2s pjA2 = __builtin_bit_cast(v2s, pjA);
        v2s pjB2 = __builtin_bit_cast(v2s, pjB);

        bool hitA = (lane == wlaneA);
        bool hitB = (lane == wlaneB);

        // ---- decrease-key + remove j, both chains interleaved ----
        SLOT_UPD(0,  pA0,  kA0,  i0,  pjA2, hitA, wslotA);
        SLOT_UPD(0,  pB0,  kB0,  i0,  pjB2, hitB, wslotB);
        SLOT_UPD(1,  pA1,  kA1,  i1,  pjA2, hitA, wslotA);
        SLOT_UPD(1,  pB1,  kB1,  i1,  pjB2, hitB, wslotB);
        SLOT_UPD(2,  pA2,  kA2,  i2,  pjA2, hitA, wslotA);
        SLOT_UPD(2,  pB2,  kB2,  i2,  pjB2, hitB, wslotB);
        SLOT_UPD(3,  pA3,  kA3,  i3,  pjA2, hitA, wslotA);
        SLOT_UPD(3,  pB3,  kB3,  i3,  pjB2, hitB, wslotB);
        SLOT_UPD(4,  pA4,  kA4,  i4,  pjA2, hitA, wslotA);
        SLOT_UPD(4,  pB4,  kB4,  i4,  pjB2, hitB, wslotB);
        SLOT_UPD(5,  pA5,  kA5,  i5,  pjA2, hitA, wslotA);
        SLOT_UPD(5,  pB5,  kB5,  i5,  pjB2, hitB, wslotB);
        SLOT_UPD(6,  pA6,  kA6,  i6,  pjA2, hitA, wslotA);
        SLOT_UPD(6,  pB6,  kB6,  i6,  pjB2, hitB, wslotB);
        SLOT_UPD(7,  pA7,  kA7,  i7,  pjA2, hitA, wslotA);
        SLOT_UPD(7,  pB7,  kB7,  i7,  pjB2, hitB, wslotB);
        SLOT_UPD(8,  pA8,  kA8,  i8,  pjA2, hitA, wslotA);
        SLOT_UPD(8,  pB8,  kB8,  i8,  pjB2, hitB, wslotB);
        SLOT_UPD(9,  pA9,  kA9,  i9,  pjA2, hitA, wslotA);
        SLOT_UPD(9,  pB9,  kB9,  i9,  pjB2, hitB, wslotB);
        SLOT_UPD(10, pA10, kA10, i10, pjA2, hitA, wslotA);
        SLOT_UPD(10, pB10, kB10, i10, pjB2, hitB, wslotB);
        SLOT_UPD(11, pA11, kA11, i11, pjA2, hitA, wslotA);
        SLOT_UPD(11, pB11, kB11, i11, pjB2, hitB, wslotB);
        SLOT_UPD(12, pA12, kA12, i12, pjA2, hitA, wslotA);
        SLOT_UPD(12, pB12, kB12, i12, pjB2, hitB, wslotB);
        SLOT_UPD(13, pA13, kA13, i13, pjA2, hitA, wslotA);
        SLOT_UPD(13, pB13, kB13, i13, pjB2, hitB, wslotB);
        SLOT_UPD(14, pA14, kA14, i14, pjA2, hitA, wslotA);
        SLOT_UPD(14, pB14, kB14, i14, pjB2, hitB, wslotB);
        SLOT_UPD(15, pA15, kA15, i15, pjA2, hitA, wslotA);
        SLOT_UPD(15, pB15, kB15, i15, pjB2, hitB, wslotB);

        INLANE_MIN16(rkA, kA);               // next iteration's per-lane min
        INLANE_MIN16(rkB, kB);
    }
}

// ---------------------------------------------------------------------------
// Kernel 4 (phase 2): recover src per edge + per-edge (Dp-Dm)^2.
// src[j] = earliest-extracted v with d2(v,j)==d2p (exact-int match) —
// provably identical to the reference's strict-'<' update history.
// ---------------------------------------------------------------------------
__global__ void recover_kernel(const unsigned* __restrict__ ptsG,
                               const unsigned* __restrict__ edgesG,
                               float* __restrict__ contrib) {
    __shared__ unsigned sS[KPTS];
    __shared__ unsigned sO[KPTS];
    __shared__ unsigned short sT[KPTS];   // extraction time + 1 (0 = root)
    int g = blockIdx.x, m = blockIdx.y;
    int tid = threadIdx.x;
    int partner = m ^ 1;

    for (int i = tid; i < KPTS; i += 256) {
        sS[i] = ptsG[m * KPTS + i];
        sO[i] = ptsG[partner * KPTS + i];
    }
    for (int e = tid; e < KPTS - 1; e += 256) {
        unsigned wkk = edgesG[m * KPTS + e];
        sT[wkk & 1023u] = (unsigned short)(e + 1);
    }
    if (tid == 0) sT[0] = 0;
    __syncthreads();

    int lane = tid & 63, w = tid >> 6;
    for (int k = 0; k < 16; k++) {
        int e = g * 64 + w * 16 + k;
        if (e >= KPTS - 1) break;            // only e=1023 (g=15,w=3,k=15)
        unsigned wk = edgesG[m * KPTS + e];
        unsigned j = wk & 1023u;
        unsigned d2p = wk >> 10;
        unsigned pj = sS[j];
        unsigned te1 = (unsigned)(e + 1);

        unsigned best = 0xFFFFFFFFu;
#pragma unroll
        for (int i = 0; i < 16; i++) {
            int v = i * 64 + lane;
            unsigned pv = sS[v];
            int d2 = dist2_packed(pv, pj);
            unsigned tv1 = (unsigned)sT[v];
            bool qual = ((unsigned)d2 == d2p) && (tv1 < te1);
            unsigned cand = qual ? ((tv1 << 10) | (unsigned)v) : 0xFFFFFFFFu;
            best = cand < best ? cand : best;
        }
#pragma unroll
        for (int dd = 32; dd; dd >>= 1) {
            unsigned o = (unsigned)__shfl_xor((int)best, dd, 64);
            best = o < best ? o : best;
        }
        unsigned vsrc = best & 1023u;
        if (lane == 0) {
            unsigned oj = sO[j], os = sO[vsrc];
            float Dp = __fsqrt_rn((float)d2p);
            float Dm = __fsqrt_rn((float)dist2_packed(oj, os));
            float diff = Dp - Dm;
            contrib[m * (KPTS - 1) + e] = diff * diff;
        }
    }
}

// ---------------------------------------------------------------------------
// Kernel 5: per-image f64 sum (extraction order, deterministic) -> loss
// ---------------------------------------------------------------------------
__global__ void final_kernel(const float* __restrict__ contrib,
                             float* __restrict__ out) {
    __shared__ double part[NIMG];
    int t = threadIdx.x;
    if (t < NIMG) {
        double s = 0.0;
        for (int e = 0; e < KPTS - 1; e++)
            s += (double)contrib[t * (KPTS - 1) + e];
        part[t] = sqrt(s);
    }
    __syncthreads();
    if (t == 0) {
        double tot = 0.0;
        for (int i = 0; i < NIMG; i++) tot += part[i];
        out[0] = (float)(0.1 * tot / 8.0);
    }
}

// ---------------------------------------------------------------------------
// ws layout:
//   [0,512K)     maskbits (lbp->select), then DEAD:
//   [0,64K)      edgesG   (mst->recover)   — overlaps dead maskbits
//   [64K,128K)   contrib  (recover->final) — overlaps dead maskbits
//   [512K,576K)  ptsG     (select->mst/recover)
// ---------------------------------------------------------------------------
extern "C" void kernel_launch(void* const* d_in, const int* in_sizes, int n_in,
                              void* d_out, int out_size, void* d_ws, size_t ws_size,
                              hipStream_t stream) {
    const float* mo = (const float*)d_in[1];   // model_output
    const float* lb = (const float*)d_in[2];   // labels

    unsigned long long* maskbits = (unsigned long long*)d_ws;
    unsigned* edgesG = (unsigned*)d_ws;
    float* contrib = (float*)((char*)d_ws + (size_t)64 * 1024);
    unsigned* ptsG = (unsigned*)((char*)d_ws + (size_t)NIMG * NWORDS * 8);
    float* out = (float*)d_out;

    lbp_kernel<<<dim3(NPIX / 256, NIMG), 256, 0, stream>>>(mo, lb, maskbits);
    select_kernel<<<NIMG, 256, 0, stream>>>(maskbits, ptsG);
    mst_kernel<<<NIMG / 2, 64, 0, stream>>>(ptsG, edgesG);
    recover_kernel<<<dim3(16, NIMG), 256, 0, stream>>>(ptsG, edgesG, contrib);
    final_kernel<<<1, 64, 0, stream>>>(contrib, out);
}

// Round 8
// 540.183 us; speedup vs baseline: 1.7202x; 1.7202x over previous
//
#include <hip/hip_runtime.h>

#define HH 512
#define WW 512
#define NPIX (HH * WW)          // 262144
#define NIMG 16
#define KPTS 1024
#define NWORDS (NPIX / 64)      // 4096 u64 mask words per image

// ---------------------------------------------------------------------------
// Kernel 1: binarize + uniform LBP (P=8,R=1) + ballot-pack mask bits
// ---------------------------------------------------------------------------
__global__ void lbp_kernel(const float* __restrict__ mo,
                           const float* __restrict__ lb,
                           unsigned long long* __restrict__ maskbits) {
#pragma clang fp contract(off)
    int m = blockIdx.y;                    // image 0..15: even=pred, odd=mask
    int pix = blockIdx.x * blockDim.x + threadIdx.x;   // 0..262143
    int r = pix >> 9, c = pix & 511;
    int sample = m >> 1;
    const float* img = (m & 1) ? (lb + sample * NPIX) : (mo + sample * NPIX);
    float thr = (m & 1) ? 0.5f : 0.0f;     // sigmoid(x)>0.5 <=> x>0

    float center = img[pix] > thr ? 1.0f : 0.0f;

    const float A = 0.70710678f;           // np.round(sin/cos, 8)
    const float drs[8] = {0.f, -A, -1.f, -A, 0.f,  A, 1.f, A};
    const float dcs[8] = {1.f,  A,  0.f, -A, -1.f, -A, 0.f, A};

    unsigned bb = 0u;
#pragma unroll
    for (int k = 0; k < 8; k++) {
        float rr = (float)r + drs[k];
        float cc = (float)c + dcs[k];
        float r0 = floorf(rr), c0 = floorf(cc);
        float fr = rr - r0,   fc = cc - c0;
        int r0i = (int)r0; r0i = max(0, min(HH - 1, r0i));
        int c0i = (int)c0; c0i = max(0, min(WW - 1, c0i));
        int r1i = min(HH - 1, r0i + 1);
        int c1i = min(WW - 1, c0i + 1);
        float g00 = img[r0i * WW + c0i] > thr ? 1.0f : 0.0f;
        float g01 = img[r0i * WW + c1i] > thr ? 1.0f : 0.0f;
        float g10 = img[r1i * WW + c0i] > thr ? 1.0f : 0.0f;
        float g11 = img[r1i * WW + c1i] > thr ? 1.0f : 0.0f;
        float s1 = (1.0f - fc) * g00 + fc * g01;
        float s2 = (1.0f - fc) * g10 + fc * g11;
        float smp = (1.0f - fr) * s1 + fr * s2;
        if (smp - center >= 0.0f) bb |= (1u << k);
    }
    unsigned rol = ((bb << 1) | (bb >> 7)) & 0xFFu;
    int changes = __popc(bb ^ rol);
    int s = __popc(bb);
    bool maskbit = (changes <= 2) && (s < 5);   // lbp < THR(=5)

    unsigned long long w = __ballot(maskbit);
    if ((threadIdx.x & 63) == 0)
        maskbits[m * NWORDS + (pix >> 6)] = w;
}

// ---------------------------------------------------------------------------
// Kernel 2: stable row-major compaction to K=1024 packed points per image
// pts entry: (r<<16)|c ; zero-padded. Shfl scan + uniform early-exit once
// K points are found (random inputs -> chunk 0 already has ~2x K).
// ---------------------------------------------------------------------------
__global__ void select_kernel(const unsigned long long* __restrict__ maskbits,
                              unsigned* __restrict__ ptsG) {
    __shared__ unsigned swv[4];
    int m = blockIdx.x, tid = threadIdx.x;
    int lane = tid & 63, wid = tid >> 6;

    for (int i = tid; i < KPTS; i += 256) ptsG[m * KPTS + i] = 0u;
    __syncthreads();

    unsigned running = 0;
    for (int ch = 0; ch < 16; ch++) {
        int w = ch * 256 + tid;
        unsigned long long word = maskbits[m * NWORDS + w];
        unsigned cnt = (unsigned)__popcll(word);

        unsigned x = cnt;                    // intra-wave inclusive scan
#pragma unroll
        for (int d = 1; d < 64; d <<= 1) {
            unsigned y = (unsigned)__shfl_up((int)x, d, 64);
            x += (lane >= d) ? y : 0u;
        }
        if (lane == 63) swv[wid] = x;
        __syncthreads();
        unsigned woff = 0, total = 0;
#pragma unroll
        for (int ww = 0; ww < 4; ww++) {
            unsigned t = swv[ww];
            total += t;
            woff += (ww < wid) ? t : 0u;
        }
        unsigned rank = running + woff + x - cnt;   // exclusive prefix
        while (word) {
            int b = __builtin_ctzll(word);
            word &= word - 1;
            if (rank < (unsigned)KPTS) {
                unsigned p = (unsigned)(w * 64 + b);
                unsigned rr = p >> 9, cc = p & 511u;
                ptsG[m * KPTS + rank] = (rr << 16) | cc;
            }
            rank++;
        }
        running += total;
        if (running >= (unsigned)KPTS) break;   // uniform -> safe
        __syncthreads();   // protect swv before next chunk
    }
}

// ---------------------------------------------------------------------------
// Kernel 3 (phase 1): single-wave Prim per image, RECORD-ONLY, ZERO LDS.
// ISSUE-BOUND (R7 A/B test: 2x work = 1.8x time) -> minimize instructions.
// Coords pre-shifted <<5 so sdot2(d,d,idx) = (d2<<10)|idx in ONE op
// (d2<2^20, idx<2^10, no carry -> bit-identical keys). Decrease-key via
// v_min_i32 (in-tree = 0xFFFFFFFF = -1 always wins; strict-< preserved).
// ---------------------------------------------------------------------------
typedef short v2s __attribute__((ext_vector_type(2)));

__device__ __forceinline__ int dist2_packed(unsigned a, unsigned b) {
#if __has_builtin(__builtin_amdgcn_sdot2)
    v2s d = __builtin_bit_cast(v2s, a) - __builtin_bit_cast(v2s, b);
    return __builtin_amdgcn_sdot2(d, d, 0, false);
#else
    int dr = (int)(a >> 16) - (int)(b >> 16);
    int dc = (int)(a & 0xFFFFu) - (int)(b & 0xFFFFu);
    return __mul24(dr, dr) + __mul24(dc, dc);
#endif
}

template <int CTRL>
__device__ __forceinline__ unsigned umin_dpp(unsigned x) {
    unsigned o = (unsigned)__builtin_amdgcn_update_dpp((int)x, (int)x, CTRL,
                                                       0xf, 0xf, false);
    return o < x ? o : x;
}

__device__ __forceinline__ unsigned umin3(unsigned a, unsigned b, unsigned c) {
    unsigned t = a < b ? a : b;          // fuses to v_min3_u32
    return t < c ? t : c;
}

// key from SHIFTED coords: sdot2 accumulates idx -> (d2<<10)+idx == (d2<<10)|idx
__device__ __forceinline__ unsigned mk_key(unsigned ps, unsigned qs, unsigned idx) {
#if __has_builtin(__builtin_amdgcn_sdot2)
    v2s d = __builtin_bit_cast(v2s, ps) - __builtin_bit_cast(v2s, qs);
    return (unsigned)__builtin_amdgcn_sdot2(d, d, (int)idx, false);
#else
    int dr = (int)(short)(ps >> 16) - (int)(short)(qs >> 16);
    int dc = (int)(short)(ps & 0xFFFFu) - (int)(short)(qs & 0xFFFFu);
    return (unsigned)(dr * dr + dc * dc + (int)idx);
#endif
}

#define SLOT_INIT(s, ps, ks, is)                                          \
    is = (unsigned)((s << 6) | lane);                                     \
    ps = base[(s << 6) | lane] << 5;    /* halves: r<<5 | c<<5 */         \
    ks = mk_key(ps, pt0s, is);

#define SLOT_UPD(s, ps, ks, is)                                           \
    { unsigned _nk = mk_key(ps, pjs, is);                                 \
      ks = (unsigned)min((int)ks, (int)_nk);  /* v_min_i32: -1 wins */    \
      ks = (hit && (wslot == (s))) ? 0xFFFFFFFFu : ks; }

#define INLANE_MIN16(res)                                                 \
    { unsigned _m0 = umin3(k0, k1, k2);                                   \
      unsigned _m1 = umin3(k3, k4, k5);                                   \
      unsigned _m2 = umin3(k6, k7, k8);                                   \
      unsigned _m3 = umin3(k9, k10, k11);                                 \
      unsigned _m4 = umin3(k12, k13, k14);                                \
      unsigned _ra = umin3(_m0, _m1, _m2);                                \
      unsigned _rb = umin3(_m3, _m4, k15);                                \
      res = _ra < _rb ? _ra : _rb; }

#define SEL16P(res)                                                       \
    { unsigned _a0 = b0 ? p1  : p0;                                       \
      unsigned _a1 = b0 ? p3  : p2;                                       \
      unsigned _a2 = b0 ? p5  : p4;                                       \
      unsigned _a3 = b0 ? p7  : p6;                                       \
      unsigned _a4 = b0 ? p9  : p8;                                       \
      unsigned _a5 = b0 ? p11 : p10;                                      \
      unsigned _a6 = b0 ? p13 : p12;                                      \
      unsigned _a7 = b0 ? p15 : p14;                                      \
      unsigned _c0 = b1 ? _a1 : _a0;                                      \
      unsigned _c1 = b1 ? _a3 : _a2;                                      \
      unsigned _c2 = b1 ? _a5 : _a4;                                      \
      unsigned _c3 = b1 ? _a7 : _a6;                                      \
      unsigned _e0 = b2 ? _c1 : _c0;                                      \
      unsigned _e1 = b2 ? _c3 : _c2;                                      \
      res = b3 ? _e1 : _e0; }

#define PIN16(P) asm volatile("" :                                        \
    "+v"(P##0), "+v"(P##1), "+v"(P##2),  "+v"(P##3),                      \
    "+v"(P##4), "+v"(P##5), "+v"(P##6),  "+v"(P##7),                      \
    "+v"(P##8), "+v"(P##9), "+v"(P##10), "+v"(P##11),                     \
    "+v"(P##12), "+v"(P##13), "+v"(P##14), "+v"(P##15))

__global__ __launch_bounds__(64, 1) void mst_kernel(const unsigned* __restrict__ ptsG,
                                                    unsigned* __restrict__ edgesG) {
    int lane = threadIdx.x;          // 0..63
    int m = blockIdx.x;
    const unsigned* base = ptsG + m * KPTS;
    unsigned pt0s = base[0] << 5;    // self point 0, shifted (uniform)

    unsigned k0,k1,k2,k3,k4,k5,k6,k7,k8,k9,k10,k11,k12,k13,k14,k15;
    unsigned p0,p1,p2,p3,p4,p5,p6,p7,p8,p9,p10,p11,p12,p13,p14,p15;
    unsigned i0,i1,i2,i3,i4,i5,i6,i7,i8,i9,i10,i11,i12,i13,i14,i15;

    SLOT_INIT(0,  p0,  k0,  i0);   SLOT_INIT(1,  p1,  k1,  i1);
    SLOT_INIT(2,  p2,  k2,  i2);   SLOT_INIT(3,  p3,  k3,  i3);
    SLOT_INIT(4,  p4,  k4,  i4);   SLOT_INIT(5,  p5,  k5,  i5);
    SLOT_INIT(6,  p6,  k6,  i6);   SLOT_INIT(7,  p7,  k7,  i7);
    SLOT_INIT(8,  p8,  k8,  i8);   SLOT_INIT(9,  p9,  k9,  i9);
    SLOT_INIT(10, p10, k10, i10);  SLOT_INIT(11, p11, k11, i11);
    SLOT_INIT(12, p12, k12, i12);  SLOT_INIT(13, p13, k13, i13);
    SLOT_INIT(14, p14, k14, i14);  SLOT_INIT(15, p15, k15, i15);

    k0 = (lane == 0) ? 0xFFFFFFFFu : k0;   // in_tree[0] = True

    unsigned* eout = edgesG + m * KPTS;
    unsigned rk;
    INLANE_MIN16(rk);

    for (int it = 0; it < KPTS - 1; it++) {
        PIN16(p); PIN16(k); PIN16(i);

        // ---- wave-64 min: 4 DPP row-folds + 4 readlane + scalar min ----
        rk = umin_dpp<0x111>(rk);   // row_shr:1
        rk = umin_dpp<0x112>(rk);   // row_shr:2
        rk = umin_dpp<0x114>(rk);   // row_shr:4
        rk = umin_dpp<0x118>(rk);   // row_shr:8 -> lane15 of each 16-row
        unsigned q0 = (unsigned)__builtin_amdgcn_readlane((int)rk, 15);
        unsigned q1 = (unsigned)__builtin_amdgcn_readlane((int)rk, 31);
        unsigned q2 = (unsigned)__builtin_amdgcn_readlane((int)rk, 47);
        unsigned q3 = (unsigned)__builtin_amdgcn_readlane((int)rk, 63);
        unsigned wa = q0 < q1 ? q0 : q1;
        unsigned wb = q2 < q3 ? q2 : q3;
        unsigned wk = wa < wb ? wa : wb;     // scalar, uniform

        unsigned j = wk & 1023u;
        int wslot = (int)(j >> 6);
        int wlane = (int)(j & 63u);

        if (lane == 0) eout[it] = wk;        // record edge (fire-and-forget)

        // ---- pj (shifted coords) from register file: SEL16 + readlane ----
        bool b0 = (wslot & 1) != 0, b1 = (wslot & 2) != 0;
        bool b2 = (wslot & 4) != 0, b3 = (wslot & 8) != 0;
        unsigned selPay;
        SEL16P(selPay);
        unsigned pjs = (unsigned)__builtin_amdgcn_readlane((int)selPay, wlane);

        bool hit = (lane == wlane);

        // ---- decrease-key + remove j (4 VALU per slot) ----
        SLOT_UPD(0,  p0,  k0,  i0);   SLOT_UPD(1,  p1,  k1,  i1);
        SLOT_UPD(2,  p2,  k2,  i2);   SLOT_UPD(3,  p3,  k3,  i3);
        SLOT_UPD(4,  p4,  k4,  i4);   SLOT_UPD(5,  p5,  k5,  i5);
        SLOT_UPD(6,  p6,  k6,  i6);   SLOT_UPD(7,  p7,  k7,  i7);
        SLOT_UPD(8,  p8,  k8,  i8);   SLOT_UPD(9,  p9,  k9,  i9);
        SLOT_UPD(10, p10, k10, i10);  SLOT_UPD(11, p11, k11, i11);
        SLOT_UPD(12, p12, k12, i12);  SLOT_UPD(13, p13, k13, i13);
        SLOT_UPD(14, p14, k14, i14);  SLOT_UPD(15, p15, k15, i15);

        INLANE_MIN16(rk);                    // next iteration's per-lane min
    }
}

// ---------------------------------------------------------------------------
// Kernel 4 (phase 2): recover src per edge + per-edge (Dp-Dm)^2.
// src[j] = earliest-extracted v with d2(v,j)==d2p (exact-int match) —
// provably identical to the reference's strict-'<' update history.
// ---------------------------------------------------------------------------
__global__ void recover_kernel(const unsigned* __restrict__ ptsG,
                               const unsigned* __restrict__ edgesG,
                               float* __restrict__ contrib) {
    __shared__ unsigned sS[KPTS];
    __shared__ unsigned sO[KPTS];
    __shared__ unsigned short sT[KPTS];   // extraction time + 1 (0 = root)
    int g = blockIdx.x, m = blockIdx.y;
    int tid = threadIdx.x;
    int partner = m ^ 1;

    for (int i = tid; i < KPTS; i += 256) {
        sS[i] = ptsG[m * KPTS + i];
        sO[i] = ptsG[partner * KPTS + i];
    }
    for (int e = tid; e < KPTS - 1; e += 256) {
        unsigned wkk = edgesG[m * KPTS + e];
        sT[wkk & 1023u] = (unsigned short)(e + 1);
    }
    if (tid == 0) sT[0] = 0;
    __syncthreads();

    int lane = tid & 63, w = tid >> 6;
    for (int k = 0; k < 16; k++) {
        int e = g * 64 + w * 16 + k;
        if (e >= KPTS - 1) break;            // only e=1023 (g=15,w=3,k=15)
        unsigned wk = edgesG[m * KPTS + e];
        unsigned j = wk & 1023u;
        unsigned d2p = wk >> 10;
        unsigned pj = sS[j];
        unsigned te1 = (unsigned)(e + 1);

        unsigned best = 0xFFFFFFFFu;
#pragma unroll
        for (int i = 0; i < 16; i++) {
            int v = i * 64 + lane;
            unsigned pv = sS[v];
            int d2 = dist2_packed(pv, pj);
            unsigned tv1 = (unsigned)sT[v];
            bool qual = ((unsigned)d2 == d2p) && (tv1 < te1);
            unsigned cand = qual ? ((tv1 << 10) | (unsigned)v) : 0xFFFFFFFFu;
            best = cand < best ? cand : best;
        }
#pragma unroll
        for (int dd = 32; dd; dd >>= 1) {
            unsigned o = (unsigned)__shfl_xor((int)best, dd, 64);
            best = o < best ? o : best;
        }
        unsigned vsrc = best & 1023u;
        if (lane == 0) {
            unsigned oj = sO[j], os = sO[vsrc];
            float Dp = __fsqrt_rn((float)d2p);
            float Dm = __fsqrt_rn((float)dist2_packed(oj, os));
            float diff = Dp - Dm;
            contrib[m * (KPTS - 1) + e] = diff * diff;
        }
    }
}

// ---------------------------------------------------------------------------
// Kernel 5: per-image f64 sum (extraction order, deterministic) -> loss
// ---------------------------------------------------------------------------
__global__ void final_kernel(const float* __restrict__ contrib,
                             float* __restrict__ out) {
    __shared__ double part[NIMG];
    int t = threadIdx.x;
    if (t < NIMG) {
        double s = 0.0;
        for (int e = 0; e < KPTS - 1; e++)
            s += (double)contrib[t * (KPTS - 1) + e];
        part[t] = sqrt(s);
    }
    __syncthreads();
    if (t == 0) {
        double tot = 0.0;
        for (int i = 0; i < NIMG; i++) tot += part[i];
        out[0] = (float)(0.1 * tot / 8.0);
    }
}

// ---------------------------------------------------------------------------
// ws layout:
//   [0,512K)     maskbits (lbp->select), then DEAD:
//   [0,64K)      edgesG   (mst->recover)   — overlaps dead maskbits
//   [64K,128K)   contrib  (recover->final) — overlaps dead maskbits
//   [512K,576K)  ptsG     (select->mst/recover)
// ---------------------------------------------------------------------------
extern "C" void kernel_launch(void* const* d_in, const int* in_sizes, int n_in,
                              void* d_out, int out_size, void* d_ws, size_t ws_size,
                              hipStream_t stream) {
    const float* mo = (const float*)d_in[1];   // model_output
    const float* lb = (const float*)d_in[2];   // labels

    unsigned long long* maskbits = (unsigned long long*)d_ws;
    unsigned* edgesG = (unsigned*)d_ws;
    float* contrib = (float*)((char*)d_ws + (size_t)64 * 1024);
    unsigned* ptsG = (unsigned*)((char*)d_ws + (size_t)NIMG * NWORDS * 8);
    float* out = (float*)d_out;

    lbp_kernel<<<dim3(NPIX / 256, NIMG), 256, 0, stream>>>(mo, lb, maskbits);
    select_kernel<<<NIMG, 256, 0, stream>>>(maskbits, ptsG);
    mst_kernel<<<NIMG, 64, 0, stream>>>(ptsG, edgesG);
    recover_kernel<<<dim3(16, NIMG), 256, 0, stream>>>(ptsG, edgesG, contrib);
    final_kernel<<<1, 64, 0, stream>>>(contrib, out);
}